// Round 18
// baseline (88.178 us; speedup 1.0000x reference)
//
#include <hip/hip_runtime.h>
#include <stdint.h>

#define HEADS 12
#define DMODEL 768
#define BATCH 2
#define SEQ 2048
#define BS (BATCH * SEQ)
#define HD 64
#define NT (SEQ / 64)

typedef float f32x4 __attribute__((ext_vector_type(4)));
typedef __bf16 bf16x8 __attribute__((ext_vector_type(8)));
typedef short s16x4 __attribute__((ext_vector_type(4)));
typedef unsigned short u16;
typedef u16 u16x8 __attribute__((ext_vector_type(8)));

__device__ __forceinline__ u16 f2b(float f) {
    return __builtin_bit_cast(u16, (__bf16)f);
}

__device__ __forceinline__ void gld_lds16(const void* g, void* l) {
    __builtin_amdgcn_global_load_lds(
        (__attribute__((address_space(1))) void*)(g),
        (__attribute__((address_space(3))) void*)(l), 16, 0, 0);
}

// ---------------- prep: fp32 -> bf16 (vectorized) ----------------
__global__ __launch_bounds__(256) void cvt_x(
    const float* __restrict__ q, const float* __restrict__ k, const float* __restrict__ v,
    u16* __restrict__ xq, u16* __restrict__ xk, u16* __restrict__ xv) {
    int z = blockIdx.z;
    const float* s = (z == 0) ? q : (z == 1) ? k : v;
    u16* d = (z == 0) ? xq : (z == 1) ? xk : xv;
    size_t i = (size_t)blockIdx.x * blockDim.x + threadIdx.x;
    const float4* s4 = (const float4*)s;
    float4 a = s4[2 * i], b = s4[2 * i + 1];
    u16x8 o;
    o[0] = f2b(a.x); o[1] = f2b(a.y); o[2] = f2b(a.z); o[3] = f2b(a.w);
    o[4] = f2b(b.x); o[5] = f2b(b.y); o[6] = f2b(b.z); o[7] = f2b(b.w);
    *(u16x8*)(d + 8 * i) = o;
}

// ---------------- prep: W -> W^T bf16 ----------------
__global__ void cvt_wt(const float* __restrict__ wq, const float* __restrict__ wk,
                       const float* __restrict__ wv,
                       u16* __restrict__ tq, u16* __restrict__ tk, u16* __restrict__ tv) {
    int z = blockIdx.z;
    const float* w = (z == 0) ? wq : (z == 1) ? wk : wv;
    u16* t = (z == 0) ? tq : (z == 1) ? tk : tv;
    __shared__ float tile[32][33];
    int tx = threadIdx.x, ty = threadIdx.y;
    int kb = blockIdx.y * 32, nb = blockIdx.x * 32;
    for (int r = 0; r < 32; r += 8)
        tile[ty + r][tx] = w[(size_t)(kb + ty + r) * DMODEL + nb + tx];
    __syncthreads();
    for (int r = 0; r < 32; r += 8)
        t[(size_t)(nb + ty + r) * DMODEL + kb + tx] = f2b(tile[tx][ty + r]);
}

// ---------------- projection GEMM: C[m][n] = X[m][k] * W[k][n] ----------------
// 128x96 tile -> grid 32x8x3 = 768 blocks = exactly 3/CU.
// z=0 -> qw [B,H,S,64] PRE-SCALED by 0.125*log2(e); z=1 -> kw [B,H,S,64];
// z=2 -> V^T CHUNKED: [bh][s/16][64 d][16 k] (each 16-key chunk = 2KB contiguous,
// so attn waves can stage their private key-slice with coalesced loads).
// z=2 uses swapped-operand MFMA (C^T fragments: row=n, col(lane)=m=s).
__global__ __launch_bounds__(256, 3) void proj_gemm(
    const u16* __restrict__ xq, const u16* __restrict__ xk, const u16* __restrict__ xv,
    const u16* __restrict__ tq, const u16* __restrict__ tk, const u16* __restrict__ tv,
    u16* __restrict__ oq, u16* __restrict__ ok, u16* __restrict__ ov) {
    const int z = blockIdx.z;
    const u16* X  = (z == 0) ? xq : (z == 1) ? xk : xv;
    const u16* WT = (z == 0) ? tq : (z == 1) ? tk : tv;
    u16* Out      = (z == 0) ? oq : (z == 1) ? ok : ov;

    __shared__ u16 As[128 * 64];   // 16 KB
    __shared__ u16 Bs[96 * 64];    // 12 KB

    const int tid = threadIdx.x;
    const int lane = tid & 63, w = tid >> 6;
    const int wm = w >> 1, wn = w & 1;          // wave tile: 64 m x 48 n
    const int m0 = blockIdx.x * 128, n0 = blockIdx.y * 96;

    f32x4 acc[4][3] = {};

    for (int kt = 0; kt < DMODEL / 64; ++kt) {
#pragma unroll
        for (int p = 0; p < 4; ++p) {
            int o = (p * 4 + w) * 1024 + lane * 16;
            int row = o >> 7;
            int col = (o & 127) ^ ((row & 7) << 4);
            gld_lds16((const char*)X + (size_t)(m0 + row) * (DMODEL * 2) + kt * 128 + col,
                      (char*)As + (p * 4 + w) * 1024);
        }
#pragma unroll
        for (int p = 0; p < 3; ++p) {
            int o = (p * 4 + w) * 1024 + lane * 16;
            int row = o >> 7;
            int col = (o & 127) ^ ((row & 7) << 4);
            gld_lds16((const char*)WT + (size_t)(n0 + row) * (DMODEL * 2) + kt * 128 + col,
                      (char*)Bs + (p * 4 + w) * 1024);
        }
        __syncthreads();
#pragma unroll
        for (int kk = 0; kk < 2; ++kk) {
            bf16x8 af[4], bfr[3];
#pragma unroll
            for (int mi = 0; mi < 4; ++mi) {
                int row = wm * 64 + mi * 16 + (lane & 15);
                int col = (kk * 64 + ((lane >> 4) << 4)) ^ ((row & 7) << 4);
                af[mi] = *(const bf16x8*)((const char*)As + row * 128 + col);
            }
#pragma unroll
            for (int ni = 0; ni < 3; ++ni) {
                int row = wn * 48 + ni * 16 + (lane & 15);
                int col = (kk * 64 + ((lane >> 4) << 4)) ^ ((row & 7) << 4);
                bfr[ni] = *(const bf16x8*)((const char*)Bs + row * 128 + col);
            }
            if (z == 2) {
#pragma unroll
                for (int mi = 0; mi < 4; ++mi)
#pragma unroll
                    for (int ni = 0; ni < 3; ++ni)
                        acc[mi][ni] = __builtin_amdgcn_mfma_f32_16x16x32_bf16(
                            bfr[ni], af[mi], acc[mi][ni], 0, 0, 0);   // C^T fragments
            } else {
#pragma unroll
                for (int mi = 0; mi < 4; ++mi)
#pragma unroll
                    for (int ni = 0; ni < 3; ++ni)
                        acc[mi][ni] = __builtin_amdgcn_mfma_f32_16x16x32_bf16(
                            af[mi], bfr[ni], acc[mi][ni], 0, 0, 0);
            }
        }
        __syncthreads();
    }

    if (z == 2) {
        // acc[mi][ni]: row=4*(lane>>4)+r -> n (=h,dd), col=lane&15 -> m (=b,s)
        const int l15 = tid & 15, g = (tid & 63) >> 4;
#pragma unroll
        for (int mi = 0; mi < 4; ++mi) {
            int mm = m0 + wm * 64 + mi * 16;
            int b = mm >> 11;
            int s16 = (mm & 2047) >> 4;
#pragma unroll
            for (int ni = 0; ni < 3; ++ni) {
#pragma unroll
                for (int r = 0; r < 4; ++r) {
                    int n = n0 + wn * 48 + ni * 16 + 4 * g + r;
                    int h = n >> 6, dd = n & 63;
                    Out[((size_t)(b * HEADS + h) * (SEQ / 16) + s16) * 1024 + dd * 16 + l15] =
                        f2b(acc[mi][ni][r]);
                }
            }
        }
    } else {
        const float mul = (z == 0) ? 0.125f * 1.44269504f : 1.0f;
#pragma unroll
        for (int mi = 0; mi < 4; ++mi) {
            int mb = m0 + wm * 64 + mi * 16 + (((tid & 63) >> 4) << 2);
#pragma unroll
            for (int ni = 0; ni < 3; ++ni) {
                int n = n0 + wn * 48 + ni * 16 + (tid & 15);
                int h = n >> 6, dd = n & 63;
#pragma unroll
                for (int r = 0; r < 4; ++r) {
                    int m = mb + r;
                    int b = m >> 11, s = m & 2047;
                    Out[((size_t)(b * HEADS + h) * SEQ + s) * HD + dd] =
                        f2b(acc[mi][ni][r] * mul);
                }
            }
        }
    }
}

// ---------------- fused attention (BARRIER-FREE key-split waves) ----------------
// Block = 64 q rows, 4 waves; wave w owns keys 16w..16w+15 of every 64-key tile,
// staged into a PRIVATE 4KB double-buffered LDS slice. No __syncthreads in the
// loop — per-wave counted vmcnt(4) keeps next-chunk loads in flight while waves
// desync freely. Fixed-max softmax -> additive partials -> cross-wave combine.
// ROUND-18 FIX vs round 17: __syncthreads() AFTER the loop, BEFORE the epilogue
// repurposes smem[0..48K) — without it a finished wave's combine-buffer writes
// clobber a still-running wave's private K/V region (the NaN race).
// qw: [B,H,S,64] pre-scaled by 0.125*log2e; kw: [B,H,S,64]; vtc: [bh][s/16][64][16]
__global__ __launch_bounds__(256, 3) void attn(
    const u16* __restrict__ qw, const u16* __restrict__ kw, const u16* __restrict__ vtc,
    const float* __restrict__ v_mask, const float* __restrict__ q_mask,
    float* __restrict__ out) {
    // loop: per-wave region 8KB (K dbuf 2x2KB | V dbuf 2x2KB), 4 waves = 32KB
    // epilogue: buf 48KB ([4 qs][3 j][16 q][64 d] f32) | lred 1KB  -> 50176 B
    __shared__ __align__(16) char smem[50176];

    const int tid = threadIdx.x;
    const int lane = tid & 63, w = tid >> 6;
    const int l15 = lane & 15, g = lane >> 4;
    const int w16 = w * 16;
    const int bh = blockIdx.y;
    const int b = bh / HEADS, h = bh % HEADS;
    const int q0 = blockIdx.x * 64;

    const u16* qb = qw + (size_t)bh * SEQ * HD;
    const char* kb = (const char*)(kw + (size_t)bh * SEQ * HD);
    const char* vcb = (const char*)vtc + (size_t)bh * 128 * 2048;  // 128 chunks x 2KB
    const float* vmaskb = v_mask + (size_t)b * SEQ;

    char* Kbase = smem + w * 8192;          // [buf][16 key rows][128B] swizzled
    char* Vbase = smem + w * 8192 + 4096;   // [buf][64 d][32B] linear

    // hoist ALL 64 q rows as B-fragments: qf[qs][kk], q = q0 + qs*16 + l15
    bf16x8 qf[4][2];
#pragma unroll
    for (int qs = 0; qs < 4; ++qs)
#pragma unroll
        for (int kk = 0; kk < 2; ++kk) {
            int row = q0 + qs * 16 + l15;
            qf[qs][kk] = *(const bf16x8*)((const char*)qb + (size_t)row * 128 + kk * 64 + (g << 4));
        }

    f32x4 accO[4][4] = {};
    float lpart[4] = {0.f, 0.f, 0.f, 0.f};

    // private stage of tile t's slice into buffer p: keys 64t+16w .. +15
    auto stage = [&](int t, int p) {
        const int kv0 = t * 64;
#pragma unroll
        for (int i = 0; i < 2; ++i) {
            int o = i * 1024 + lane * 16;
            int row = o >> 7;                       // 0..15
            int col = (o & 127) ^ ((row & 7) << 4);
            gld_lds16(kb + (size_t)(kv0 + w16 + row) * 128 + col,
                      Kbase + p * 2048 + i * 1024);
        }
        const char* chunk = vcb + (size_t)(4 * t + w) * 2048;
#pragma unroll
        for (int i = 0; i < 2; ++i)
            gld_lds16(chunk + i * 1024 + lane * 16, Vbase + p * 2048 + i * 1024);
    };

    stage(0, 0);

    for (int t = 0; t < NT; ++t) {
        const int cur = t & 1;
        // cur-chunk mask -> registers (issued ahead of next-stage loads)
        f32x4 vm = *(const f32x4*)(vmaskb + t * 64 + w16 + 4 * g);
        stage((t + 1) & (NT - 1), cur ^ 1);   // t=NT-1 wraps: benign re-stage

        // counted drain: keep next's 4 loads in flight; cur's 4 + mask done
        asm volatile("s_waitcnt vmcnt(4)" ::: "memory");

        const char* KsC = Kbase + cur * 2048;
        const char* VsC = Vbase + cur * 2048;

        bf16x8 kf[2];
#pragma unroll
        for (int kk = 0; kk < 2; ++kk)
            kf[kk] = *(const bf16x8*)(KsC + l15 * 128 +
                                      ((kk * 64 + (g << 4)) ^ ((l15 & 7) << 4)));
        s16x4 vvf[4];
#pragma unroll
        for (int dt = 0; dt < 4; ++dt)
            vvf[dt] = *(const s16x4*)(VsC + (dt * 16 + l15) * 32 + g * 8);

        f32x4 bbv;
#pragma unroll
        for (int r = 0; r < 4; ++r)
            bbv[r] = fmaf(vm[r], 1.442695e10f, -1.442695e10f);

        // ---- S^T slice = K_w Q^T (8 MFMA): sc[qs][r]=S[key=16w+4g+r][q=qs*16+l15]
        f32x4 sc[4] = {};
        __builtin_amdgcn_s_setprio(1);
#pragma unroll
        for (int kk = 0; kk < 2; ++kk)
#pragma unroll
            for (int qs = 0; qs < 4; ++qs)
                sc[qs] = __builtin_amdgcn_mfma_f32_16x16x32_bf16(
                    kf[kk], qf[qs][kk], sc[qs], 0, 0, 0);
        __builtin_amdgcn_s_setprio(0);

        // ---- fixed-max softmax; P stays in registers
        s16x4 pb[4];
#pragma unroll
        for (int qs = 0; qs < 4; ++qs) {
            float ls = 0.f;
#pragma unroll
            for (int r = 0; r < 4; ++r) {
                float p = __builtin_amdgcn_exp2f(sc[qs][r] + bbv[r]);
                ls += p;
                pb[qs][r] = (short)f2b(p);
            }
            lpart[qs] += ls;
        }

        // ---- O^T partial += V_w^T P_w^T (16 x K=16 MFMA), operands in regs
        __builtin_amdgcn_s_setprio(1);
#pragma unroll
        for (int qs = 0; qs < 4; ++qs)
#pragma unroll
            for (int dt = 0; dt < 4; ++dt)
                accO[qs][dt] = __builtin_amdgcn_mfma_f32_16x16x16bf16_1k(
                    vvf[dt], pb[qs], accO[qs][dt], 0, 0, 0);
        __builtin_amdgcn_s_setprio(0);
    }

    // drain the wrap-around stage, then BARRIER before smem is repurposed:
    // without this, a finished wave's combine writes race a running wave's K/V.
    asm volatile("s_waitcnt vmcnt(0)" ::: "memory");
    __syncthreads();

    // ---- epilogue: cross-wave additive combine (round-13 proven, rule #20 safe)
    float* buf  = (float*)smem;                  // [qs][j][16 q][64 d]
    float* lred = (float*)(smem + 49152);        // [w][qs][16]

    float lq[4];
#pragma unroll
    for (int qs = 0; qs < 4; ++qs) {
        float v = lpart[qs];
        v += __shfl_xor(v, 16);
        v += __shfl_xor(v, 32);
        lq[qs] = v;
    }
    if (g == 0)
#pragma unroll
        for (int qs = 0; qs < 4; ++qs)
            lred[(w * 4 + qs) * 16 + l15] = lq[qs];

    f32x4 own[4] = {};
#pragma unroll
    for (int qs = 0; qs < 4; ++qs)
        if (qs == w) {
#pragma unroll
            for (int dt = 0; dt < 4; ++dt) own[dt] = accO[qs][dt];
        }

#pragma unroll
    for (int qs = 0; qs < 4; ++qs) {
        if (qs == w) continue;                   // runtime branch, static indices
        int j = (w < qs) ? w : w - 1;
        float* slot = buf + ((qs * 3 + j) * 16 + l15) * 64;
#pragma unroll
        for (int dt = 0; dt < 4; ++dt)
            *(f32x4*)(slot + dt * 16 + 4 * g) = accO[qs][dt];
    }
    __syncthreads();

    {
#pragma unroll
        for (int j = 0; j < 3; ++j) {
            const float* slot = buf + ((w * 3 + j) * 16 + l15) * 64;
#pragma unroll
            for (int dt = 0; dt < 4; ++dt)
                own[dt] += *(const f32x4*)(slot + dt * 16 + 4 * g);
        }
        float ltot = lred[(0 * 4 + w) * 16 + l15] + lred[(1 * 4 + w) * 16 + l15] +
                     lred[(2 * 4 + w) * 16 + l15] + lred[(3 * 4 + w) * 16 + l15];
        int qrow = q0 + w16 + l15;
        float qm = q_mask[(size_t)b * SEQ + qrow];
        float inv = (ltot > 0.f) ? qm / ltot : 0.f;
#pragma unroll
        for (int dt = 0; dt < 4; ++dt) {
            f32x4 o = own[dt] * inv;
            *(f32x4*)(&out[((size_t)b * SEQ + qrow) * 768 + h * HD + dt * 16 + 4 * g]) = o;
        }
    }
}

extern "C" void kernel_launch(void* const* d_in, const int* in_sizes, int n_in,
                              void* d_out, int out_size, void* d_ws, size_t ws_size,
                              hipStream_t stream) {
    const float* q      = (const float*)d_in[0];
    const float* k      = (const float*)d_in[1];
    const float* v      = (const float*)d_in[2];
    const float* vmask  = (const float*)d_in[3];
    const float* qmask  = (const float*)d_in[4];
    const float* Wq     = (const float*)d_in[5];
    const float* Wk     = (const float*)d_in[6];
    const float* Wv     = (const float*)d_in[7];
    float* out = (float*)d_out;

    u16* Xq  = (u16*)d_ws;
    u16* Xk  = Xq + (size_t)BS * DMODEL;
    u16* Xv  = Xk + (size_t)BS * DMODEL;
    u16* WTq = Xv + (size_t)BS * DMODEL;
    u16* WTk = WTq + (size_t)DMODEL * DMODEL;
    u16* WTv = WTk + (size_t)DMODEL * DMODEL;
    u16* qwp = WTv + (size_t)DMODEL * DMODEL;
    u16* kwp = qwp + (size_t)BATCH * HEADS * SEQ * HD;
    u16* vtp = kwp + (size_t)BATCH * HEADS * SEQ * HD;

    cvt_x<<<dim3(BS * DMODEL / 8 / 256, 1, 3), 256, 0, stream>>>(q, k, v, Xq, Xk, Xv);
    cvt_wt<<<dim3(DMODEL / 32, DMODEL / 32, 3), dim3(32, 8), 0, stream>>>(
        Wq, Wk, Wv, WTq, WTk, WTv);
    proj_gemm<<<dim3(BS / 128, DMODEL / 96, 3), 256, 0, stream>>>(
        Xq, Xk, Xv, WTq, WTk, WTv, qwp, kwp, vtp);
    attn<<<dim3(SEQ / 64, BATCH * HEADS), 256, 0, stream>>>(
        qwp, kwp, vtp, vmask, qmask, out);
}

// Round 19
// 84.880 us; speedup vs baseline: 1.0388x; 1.0388x over previous
//
#include <hip/hip_runtime.h>
#include <stdint.h>

#define HEADS 12
#define DMODEL 768
#define BATCH 2
#define SEQ 2048
#define BS (BATCH * SEQ)
#define HD 64

typedef float f32x4 __attribute__((ext_vector_type(4)));
typedef __bf16 bf16x8 __attribute__((ext_vector_type(8)));
typedef short s16x4 __attribute__((ext_vector_type(4)));
typedef unsigned short u16;
typedef u16 u16x8 __attribute__((ext_vector_type(8)));

__device__ __forceinline__ u16 f2b(float f) {
    return __builtin_bit_cast(u16, (__bf16)f);
}

__device__ __forceinline__ void gld_lds16(const void* g, void* l) {
    __builtin_amdgcn_global_load_lds(
        (__attribute__((address_space(1))) void*)(g),
        (__attribute__((address_space(3))) void*)(l), 16, 0, 0);
}
__device__ __forceinline__ void gld_lds4(const void* g, void* l) {
    __builtin_amdgcn_global_load_lds(
        (__attribute__((address_space(1))) void*)(g),
        (__attribute__((address_space(3))) void*)(l), 4, 0, 0);
}

// ---------------- prep: W -> W^T bf16 ----------------
__global__ void cvt_wt(const float* __restrict__ wq, const float* __restrict__ wk,
                       const float* __restrict__ wv,
                       u16* __restrict__ tq, u16* __restrict__ tk, u16* __restrict__ tv) {
    int z = blockIdx.z;
    const float* w = (z == 0) ? wq : (z == 1) ? wk : wv;
    u16* t = (z == 0) ? tq : (z == 1) ? tk : tv;
    __shared__ float tile[32][33];
    int tx = threadIdx.x, ty = threadIdx.y;
    int kb = blockIdx.y * 32, nb = blockIdx.x * 32;
    for (int r = 0; r < 32; r += 8)
        tile[ty + r][tx] = w[(size_t)(kb + ty + r) * DMODEL + nb + tx];
    __syncthreads();
    for (int r = 0; r < 32; r += 8)
        t[(size_t)(nb + ty + r) * DMODEL + kb + tx] = f2b(tile[tx][ty + r]);
}

// ---------------- projection GEMM: C[m][n] = X_fp32[m][k] * W[k][n] ------------
// Round-19: cvt_x kernel DELETED — A-tiles are reg-staged straight from the raw
// fp32 inputs (2x float4 per lane), converted to bf16 in-register, and written
// to the SWIZZLED LDS address (write-swz + read-swz, rule #21 consistent).
// Saves the 56.6MB cvt round-trip; X re-reads come from L2/L3.
// 128x96 tile -> grid 32x8x3 = 768 blocks = exactly 3/CU.
// z=0 -> qw [B,H,S,64] PRE-SCALED by 0.125*log2(e); z=1 -> kw [B,H,S,64];
// z=2 -> vt [B,H,64,S] via swapped-operand MFMA (C^T fragments, coalesced stores)
__global__ __launch_bounds__(256, 3) void proj_gemm(
    const float* __restrict__ xq, const float* __restrict__ xk, const float* __restrict__ xv,
    const u16* __restrict__ tq, const u16* __restrict__ tk, const u16* __restrict__ tv,
    u16* __restrict__ oq, u16* __restrict__ ok, u16* __restrict__ ov) {
    const int z = blockIdx.z;
    const float* X = (z == 0) ? xq : (z == 1) ? xk : xv;
    const u16* WT = (z == 0) ? tq : (z == 1) ? tk : tv;
    u16* Out      = (z == 0) ? oq : (z == 1) ? ok : ov;

    __shared__ u16 As[128 * 64];   // 16 KB
    __shared__ u16 Bs[96 * 64];    // 12 KB

    const int tid = threadIdx.x;
    const int lane = tid & 63, w = tid >> 6;
    const int wm = w >> 1, wn = w & 1;          // wave tile: 64 m x 48 n
    const int m0 = blockIdx.x * 128, n0 = blockIdx.y * 96;

    f32x4 acc[4][3] = {};

    for (int kt = 0; kt < DMODEL / 64; ++kt) {
        // ---- A: load raw fp32 (8 elems/lane), convert later
        float4 xa[4], xb[4];
#pragma unroll
        for (int p = 0; p < 4; ++p) {
            int o = (p * 4 + w) * 1024 + lane * 16;
            int row = o >> 7, colb = o & 127;
            const float* src = X + (size_t)(m0 + row) * DMODEL + kt * 64 + (colb >> 1);
            xa[p] = *(const float4*)(src);
            xb[p] = *(const float4*)(src + 4);
        }
        // ---- B: async gld (overlaps the A-converts)
#pragma unroll
        for (int p = 0; p < 3; ++p) {
            int o = (p * 4 + w) * 1024 + lane * 16;
            int row = o >> 7;
            int col = (o & 127) ^ ((row & 7) << 4);
            gld_lds16((const char*)WT + (size_t)(n0 + row) * (DMODEL * 2) + kt * 128 + col,
                      (char*)Bs + (p * 4 + w) * 1024);
        }
        // ---- A: convert + swizzled ds_write
#pragma unroll
        for (int p = 0; p < 4; ++p) {
            int o = (p * 4 + w) * 1024 + lane * 16;
            int row = o >> 7, colb = o & 127;
            u16x8 v8;
            v8[0] = f2b(xa[p].x); v8[1] = f2b(xa[p].y);
            v8[2] = f2b(xa[p].z); v8[3] = f2b(xa[p].w);
            v8[4] = f2b(xb[p].x); v8[5] = f2b(xb[p].y);
            v8[6] = f2b(xb[p].z); v8[7] = f2b(xb[p].w);
            *(u16x8*)((char*)As + row * 128 + (colb ^ ((row & 7) << 4))) = v8;
        }
        __syncthreads();
#pragma unroll
        for (int kk = 0; kk < 2; ++kk) {
            bf16x8 af[4], bfr[3];
#pragma unroll
            for (int mi = 0; mi < 4; ++mi) {
                int row = wm * 64 + mi * 16 + (lane & 15);
                int col = (kk * 64 + ((lane >> 4) << 4)) ^ ((row & 7) << 4);
                af[mi] = *(const bf16x8*)((const char*)As + row * 128 + col);
            }
#pragma unroll
            for (int ni = 0; ni < 3; ++ni) {
                int row = wn * 48 + ni * 16 + (lane & 15);
                int col = (kk * 64 + ((lane >> 4) << 4)) ^ ((row & 7) << 4);
                bfr[ni] = *(const bf16x8*)((const char*)Bs + row * 128 + col);
            }
            if (z == 2) {
#pragma unroll
                for (int mi = 0; mi < 4; ++mi)
#pragma unroll
                    for (int ni = 0; ni < 3; ++ni)
                        acc[mi][ni] = __builtin_amdgcn_mfma_f32_16x16x32_bf16(
                            bfr[ni], af[mi], acc[mi][ni], 0, 0, 0);   // C^T fragments
            } else {
#pragma unroll
                for (int mi = 0; mi < 4; ++mi)
#pragma unroll
                    for (int ni = 0; ni < 3; ++ni)
                        acc[mi][ni] = __builtin_amdgcn_mfma_f32_16x16x32_bf16(
                            af[mi], bfr[ni], acc[mi][ni], 0, 0, 0);
            }
        }
        __syncthreads();
    }

    if (z == 2) {
        // acc[mi][ni]: row=4*(lane>>4)+r -> n (=h,dd), col=lane&15 -> m (=b,s)
        const int m = m0 + wm * 64 + (tid & 15);
        const int b = m >> 11;
#pragma unroll
        for (int mi = 0; mi < 4; ++mi) {
            int s = ((m + mi * 16) & 2047);
#pragma unroll
            for (int ni = 0; ni < 3; ++ni) {
                int nb2 = n0 + wn * 48 + ni * 16 + (((tid & 63) >> 4) << 2);
#pragma unroll
                for (int r = 0; r < 4; ++r) {
                    int n = nb2 + r;
                    int h = n >> 6, dd = n & 63;
                    Out[((size_t)(b * HEADS + h) * HD + dd) * SEQ + s] =
                        f2b(acc[mi][ni][r]);
                }
            }
        }
    } else {
        const float mul = (z == 0) ? 0.125f * 1.44269504f : 1.0f;
#pragma unroll
        for (int mi = 0; mi < 4; ++mi) {
            int mb = m0 + wm * 64 + mi * 16 + (((tid & 63) >> 4) << 2);
#pragma unroll
            for (int ni = 0; ni < 3; ++ni) {
                int n = n0 + wn * 48 + ni * 16 + (tid & 15);
                int h = n >> 6, dd = n & 63;
#pragma unroll
                for (int r = 0; r < 4; ++r) {
                    int m = mb + r;
                    int b = m >> 11, s = m & 2047;
                    Out[((size_t)(b * HEADS + h) * SEQ + s) * HD + dd] =
                        f2b(acc[mi][ni][r] * mul);
                }
            }
        }
    }
}

// ---------------- fused attention (round-13/16 proven; byte-identical) ----------
// Block = 64 q rows, 4 waves. Wave w owns KEYS 16w..16w+15 of every tile and
// computes them against ALL 64 q (Q hoisted x4). Fixed-max softmax makes l/O
// partials purely additive -> cross-wave combine ONCE per block (LDS epilogue).
// qw: [B,H,S,64] bf16 pre-scaled by 0.125*log2e; kw: [B,H,S,64]; vt: [B,H,64,S]
__global__ __launch_bounds__(256, 3) void attn(
    const u16* __restrict__ qw, const u16* __restrict__ kw, const u16* __restrict__ vt,
    const float* __restrict__ v_mask, const float* __restrict__ q_mask,
    float* __restrict__ out) {
    // loop phase:  Ks[2] 16KB | Vs[2] 16KB | bias[2] 512B   (33,280 B)
    // epilogue:    buf 48KB ([4 qs][3 j][16 q][64 d] f32) | lred 1KB
    __shared__ __align__(16) char smem[50176];

    const int tid = threadIdx.x;
    const int lane = tid & 63, w = tid >> 6;
    const int l15 = lane & 15, g = lane >> 4;
    const int w16 = w * 16;
    const int bh = blockIdx.y;
    const int b = bh / HEADS, h = bh % HEADS;
    const int q0 = blockIdx.x * 64;

    const u16* qb = qw + (size_t)bh * SEQ * HD;
    const u16* kb = kw + (size_t)bh * SEQ * HD;
    const u16* vb = vt + (size_t)bh * HD * SEQ;
    const float* vmaskb = v_mask + (size_t)b * SEQ;

    bf16x8 qf[4][2];
#pragma unroll
    for (int qs = 0; qs < 4; ++qs)
#pragma unroll
        for (int kk = 0; kk < 2; ++kk) {
            int row = q0 + qs * 16 + l15;
            qf[qs][kk] = *(const bf16x8*)((const char*)qb + (size_t)row * 128 + kk * 64 + (g << 4));
        }

    f32x4 accO[4][4] = {};
    float lpart[4] = {0.f, 0.f, 0.f, 0.f};

    auto stage = [&](int t, int p) {
        const int kv0 = t * 64;
#pragma unroll
        for (int i = 0; i < 2; ++i) {
            int o = (i * 4 + w) * 1024 + lane * 16;
            int row = o >> 7;
            int col = (o & 127) ^ ((row & 7) << 4);
            gld_lds16((const char*)kb + (size_t)(kv0 + row) * 128 + col,
                      smem + p * 8192 + (i * 4 + w) * 1024);
            gld_lds16((const char*)vb + (size_t)row * (SEQ * 2) + (size_t)kv0 * 2 + col,
                      smem + 16384 + p * 8192 + (i * 4 + w) * 1024);
        }
        gld_lds4(vmaskb + kv0 + lane, smem + 32768 + p * 256);
    };

    stage(0, 0);
    __syncthreads();

    for (int t = 0; t < SEQ / 64; ++t) {
        const int cur = t & 1;
        if (t + 1 < SEQ / 64) stage(t + 1, cur ^ 1);
        const char* KsC = smem + cur * 8192;
        const char* VsC = smem + 16384 + cur * 8192;
        const float* biasC = (const float*)(smem + 32768 + cur * 256);

        bf16x8 kf[2];
        {
            int row = w16 + l15;
#pragma unroll
            for (int kk = 0; kk < 2; ++kk)
                kf[kk] = *(const bf16x8*)(KsC + row * 128 +
                                          ((kk * 64 + (g << 4)) ^ ((row & 7) << 4)));
        }
        s16x4 vvf[4];
#pragma unroll
        for (int dt = 0; dt < 4; ++dt) {
            int row = dt * 16 + l15;
            vvf[dt] = *(const s16x4*)(VsC + row * 128 +
                                      ((w16 * 2 + g * 8) ^ ((row & 7) << 4)));
        }
        f32x4 vm = *(const f32x4*)(biasC + w16 + 4 * g);
        f32x4 bbv;
#pragma unroll
        for (int r = 0; r < 4; ++r)
            bbv[r] = fmaf(vm[r], 1.442695e10f, -1.442695e10f);

        f32x4 sc[4] = {};
#pragma unroll
        for (int kk = 0; kk < 2; ++kk)
#pragma unroll
            for (int qs = 0; qs < 4; ++qs)
                sc[qs] = __builtin_amdgcn_mfma_f32_16x16x32_bf16(
                    kf[kk], qf[qs][kk], sc[qs], 0, 0, 0);

        s16x4 pb[4];
#pragma unroll
        for (int qs = 0; qs < 4; ++qs) {
            float ls = 0.f;
#pragma unroll
            for (int r = 0; r < 4; ++r) {
                float p = __builtin_amdgcn_exp2f(sc[qs][r] + bbv[r]);
                ls += p;
                pb[qs][r] = (short)f2b(p);
            }
            lpart[qs] += ls;
        }

#pragma unroll
        for (int qs = 0; qs < 4; ++qs)
#pragma unroll
            for (int dt = 0; dt < 4; ++dt)
                accO[qs][dt] = __builtin_amdgcn_mfma_f32_16x16x16bf16_1k(
                    vvf[dt], pb[qs], accO[qs][dt], 0, 0, 0);

        __syncthreads();
    }

    float* buf  = (float*)smem;                  // [qs][j][16 q][64 d]
    float* lred = (float*)(smem + 49152);        // [w][qs][16]

    float lq[4];
#pragma unroll
    for (int qs = 0; qs < 4; ++qs) {
        float v = lpart[qs];
        v += __shfl_xor(v, 16);
        v += __shfl_xor(v, 32);
        lq[qs] = v;
    }
    if (g == 0)
#pragma unroll
        for (int qs = 0; qs < 4; ++qs)
            lred[(w * 4 + qs) * 16 + l15] = lq[qs];

    f32x4 own[4] = {};
#pragma unroll
    for (int qs = 0; qs < 4; ++qs)
        if (qs == w) {
#pragma unroll
            for (int dt = 0; dt < 4; ++dt) own[dt] = accO[qs][dt];
        }

#pragma unroll
    for (int qs = 0; qs < 4; ++qs) {
        if (qs == w) continue;                   // runtime branch, static indices
        int j = (w < qs) ? w : w - 1;
        float* slot = buf + ((qs * 3 + j) * 16 + l15) * 64;
#pragma unroll
        for (int dt = 0; dt < 4; ++dt)
            *(f32x4*)(slot + dt * 16 + 4 * g) = accO[qs][dt];
    }
    __syncthreads();

    {
#pragma unroll
        for (int j = 0; j < 3; ++j) {
            const float* slot = buf + ((w * 3 + j) * 16 + l15) * 64;
#pragma unroll
            for (int dt = 0; dt < 4; ++dt)
                own[dt] += *(const f32x4*)(slot + dt * 16 + 4 * g);
        }
        float ltot = lred[(0 * 4 + w) * 16 + l15] + lred[(1 * 4 + w) * 16 + l15] +
                     lred[(2 * 4 + w) * 16 + l15] + lred[(3 * 4 + w) * 16 + l15];
        int qrow = q0 + w16 + l15;
        float qm = q_mask[(size_t)b * SEQ + qrow];
        float inv = (ltot > 0.f) ? qm / ltot : 0.f;
#pragma unroll
        for (int dt = 0; dt < 4; ++dt) {
            f32x4 o = own[dt] * inv;
            *(f32x4*)(&out[((size_t)b * SEQ + qrow) * 768 + h * HD + dt * 16 + 4 * g]) = o;
        }
    }
}

extern "C" void kernel_launch(void* const* d_in, const int* in_sizes, int n_in,
                              void* d_out, int out_size, void* d_ws, size_t ws_size,
                              hipStream_t stream) {
    const float* q      = (const float*)d_in[0];
    const float* k      = (const float*)d_in[1];
    const float* v      = (const float*)d_in[2];
    const float* vmask  = (const float*)d_in[3];
    const float* qmask  = (const float*)d_in[4];
    const float* Wq     = (const float*)d_in[5];
    const float* Wk     = (const float*)d_in[6];
    const float* Wv     = (const float*)d_in[7];
    float* out = (float*)d_out;

    u16* WTq = (u16*)d_ws;
    u16* WTk = WTq + (size_t)DMODEL * DMODEL;
    u16* WTv = WTk + (size_t)DMODEL * DMODEL;
    u16* qwp = WTv + (size_t)DMODEL * DMODEL;
    u16* kwp = qwp + (size_t)BATCH * HEADS * SEQ * HD;
    u16* vtp = kwp + (size_t)BATCH * HEADS * SEQ * HD;

    cvt_wt<<<dim3(DMODEL / 32, DMODEL / 32, 3), dim3(32, 8), 0, stream>>>(
        Wq, Wk, Wv, WTq, WTk, WTv);
    proj_gemm<<<dim3(BS / 128, DMODEL / 96, 3), 256, 0, stream>>>(
        q, k, v, WTq, WTk, WTv, qwp, kwp, vtp);
    attn<<<dim3(SEQ / 64, BATCH * HEADS), 256, 0, stream>>>(
        qwp, kwp, vtp, vmask, qmask, out);
}

// Round 20
// 82.883 us; speedup vs baseline: 1.0639x; 1.0241x over previous
//
#include <hip/hip_runtime.h>
#include <stdint.h>

#define HEADS 12
#define DMODEL 768
#define BATCH 2
#define SEQ 2048
#define BS (BATCH * SEQ)
#define HD 64

typedef float f32x4 __attribute__((ext_vector_type(4)));
typedef __bf16 bf16x8 __attribute__((ext_vector_type(8)));
typedef short s16x4 __attribute__((ext_vector_type(4)));
typedef unsigned short u16;
typedef u16 u16x8 __attribute__((ext_vector_type(8)));

__device__ __forceinline__ u16 f2b(float f) {
    return __builtin_bit_cast(u16, (__bf16)f);
}

__device__ __forceinline__ void gld_lds16(const void* g, void* l) {
    __builtin_amdgcn_global_load_lds(
        (__attribute__((address_space(1))) void*)(g),
        (__attribute__((address_space(3))) void*)(l), 16, 0, 0);
}
__device__ __forceinline__ void gld_lds4(const void* g, void* l) {
    __builtin_amdgcn_global_load_lds(
        (__attribute__((address_space(1))) void*)(g),
        (__attribute__((address_space(3))) void*)(l), 4, 0, 0);
}

// ---------------- prep: W -> W^T bf16 ----------------
__global__ void cvt_wt(const float* __restrict__ wq, const float* __restrict__ wk,
                       const float* __restrict__ wv,
                       u16* __restrict__ tq, u16* __restrict__ tk, u16* __restrict__ tv) {
    int z = blockIdx.z;
    const float* w = (z == 0) ? wq : (z == 1) ? wk : wv;
    u16* t = (z == 0) ? tq : (z == 1) ? tk : tv;
    __shared__ float tile[32][33];
    int tx = threadIdx.x, ty = threadIdx.y;
    int kb = blockIdx.y * 32, nb = blockIdx.x * 32;
    for (int r = 0; r < 32; r += 8)
        tile[ty + r][tx] = w[(size_t)(kb + ty + r) * DMODEL + nb + tx];
    __syncthreads();
    for (int r = 0; r < 32; r += 8)
        t[(size_t)(nb + ty + r) * DMODEL + kb + tx] = f2b(tile[tx][ty + r]);
}

// ---------------- projection GEMM: C[m][n] = X_fp32[m][k] * W[k][n] ------------
// Round-19 proven: cvt_x fused (A reg-staged fp32 -> bf16 -> swizzled ds_write).
// 128x96 tile -> grid 32x8x3 = 768 blocks = exactly 3/CU.
// z=0 -> qw pre-scaled by 0.125*log2e; z=1 -> kw; z=2 -> vt [B,H,64,S] via
// swapped-operand MFMA (C^T fragments, coalesced stores).
__global__ __launch_bounds__(256, 3) void proj_gemm(
    const float* __restrict__ xq, const float* __restrict__ xk, const float* __restrict__ xv,
    const u16* __restrict__ tq, const u16* __restrict__ tk, const u16* __restrict__ tv,
    u16* __restrict__ oq, u16* __restrict__ ok, u16* __restrict__ ov) {
    const int z = blockIdx.z;
    const float* X = (z == 0) ? xq : (z == 1) ? xk : xv;
    const u16* WT = (z == 0) ? tq : (z == 1) ? tk : tv;
    u16* Out      = (z == 0) ? oq : (z == 1) ? ok : ov;

    __shared__ u16 As[128 * 64];   // 16 KB
    __shared__ u16 Bs[96 * 64];    // 12 KB

    const int tid = threadIdx.x;
    const int lane = tid & 63, w = tid >> 6;
    const int wm = w >> 1, wn = w & 1;          // wave tile: 64 m x 48 n
    const int m0 = blockIdx.x * 128, n0 = blockIdx.y * 96;

    f32x4 acc[4][3] = {};

    for (int kt = 0; kt < DMODEL / 64; ++kt) {
        float4 xa[4], xb[4];
#pragma unroll
        for (int p = 0; p < 4; ++p) {
            int o = (p * 4 + w) * 1024 + lane * 16;
            int row = o >> 7, colb = o & 127;
            const float* src = X + (size_t)(m0 + row) * DMODEL + kt * 64 + (colb >> 1);
            xa[p] = *(const float4*)(src);
            xb[p] = *(const float4*)(src + 4);
        }
#pragma unroll
        for (int p = 0; p < 3; ++p) {
            int o = (p * 4 + w) * 1024 + lane * 16;
            int row = o >> 7;
            int col = (o & 127) ^ ((row & 7) << 4);
            gld_lds16((const char*)WT + (size_t)(n0 + row) * (DMODEL * 2) + kt * 128 + col,
                      (char*)Bs + (p * 4 + w) * 1024);
        }
#pragma unroll
        for (int p = 0; p < 4; ++p) {
            int o = (p * 4 + w) * 1024 + lane * 16;
            int row = o >> 7, colb = o & 127;
            u16x8 v8;
            v8[0] = f2b(xa[p].x); v8[1] = f2b(xa[p].y);
            v8[2] = f2b(xa[p].z); v8[3] = f2b(xa[p].w);
            v8[4] = f2b(xb[p].x); v8[5] = f2b(xb[p].y);
            v8[6] = f2b(xb[p].z); v8[7] = f2b(xb[p].w);
            *(u16x8*)((char*)As + row * 128 + (colb ^ ((row & 7) << 4))) = v8;
        }
        __syncthreads();
#pragma unroll
        for (int kk = 0; kk < 2; ++kk) {
            bf16x8 af[4], bfr[3];
#pragma unroll
            for (int mi = 0; mi < 4; ++mi) {
                int row = wm * 64 + mi * 16 + (lane & 15);
                int col = (kk * 64 + ((lane >> 4) << 4)) ^ ((row & 7) << 4);
                af[mi] = *(const bf16x8*)((const char*)As + row * 128 + col);
            }
#pragma unroll
            for (int ni = 0; ni < 3; ++ni) {
                int row = wn * 48 + ni * 16 + (lane & 15);
                int col = (kk * 64 + ((lane >> 4) << 4)) ^ ((row & 7) << 4);
                bfr[ni] = *(const bf16x8*)((const char*)Bs + row * 128 + col);
            }
            if (z == 2) {
#pragma unroll
                for (int mi = 0; mi < 4; ++mi)
#pragma unroll
                    for (int ni = 0; ni < 3; ++ni)
                        acc[mi][ni] = __builtin_amdgcn_mfma_f32_16x16x32_bf16(
                            bfr[ni], af[mi], acc[mi][ni], 0, 0, 0);   // C^T fragments
            } else {
#pragma unroll
                for (int mi = 0; mi < 4; ++mi)
#pragma unroll
                    for (int ni = 0; ni < 3; ++ni)
                        acc[mi][ni] = __builtin_amdgcn_mfma_f32_16x16x32_bf16(
                            af[mi], bfr[ni], acc[mi][ni], 0, 0, 0);
            }
        }
        __syncthreads();
    }

    if (z == 2) {
        const int m = m0 + wm * 64 + (tid & 15);
        const int b = m >> 11;
#pragma unroll
        for (int mi = 0; mi < 4; ++mi) {
            int s = ((m + mi * 16) & 2047);
#pragma unroll
            for (int ni = 0; ni < 3; ++ni) {
                int nb2 = n0 + wn * 48 + ni * 16 + (((tid & 63) >> 4) << 2);
#pragma unroll
                for (int r = 0; r < 4; ++r) {
                    int n = nb2 + r;
                    int h = n >> 6, dd = n & 63;
                    Out[((size_t)(b * HEADS + h) * HD + dd) * SEQ + s] =
                        f2b(acc[mi][ni][r]);
                }
            }
        }
    } else {
        const float mul = (z == 0) ? 0.125f * 1.44269504f : 1.0f;
#pragma unroll
        for (int mi = 0; mi < 4; ++mi) {
            int mb = m0 + wm * 64 + mi * 16 + (((tid & 63) >> 4) << 2);
#pragma unroll
            for (int ni = 0; ni < 3; ++ni) {
                int n = n0 + wn * 48 + ni * 16 + (tid & 15);
                int h = n >> 6, dd = n & 63;
#pragma unroll
                for (int r = 0; r < 4; ++r) {
                    int m = mb + r;
                    int b = m >> 11, s = m & 2047;
                    Out[((size_t)(b * HEADS + h) * SEQ + s) * HD + dd] =
                        f2b(acc[mi][ni][r] * mul);
                }
            }
        }
    }
}

// ---------------- fused attention (key-split waves + VALU diet) ----------------
// Round-16 structure. Round-20 deltas: (1) l computed via MFMA with all-ones
// A-fragment (C rows all equal column-sum -> l[q=l15] lane-resident; kills 16
// adds/tile + the epilogue shuffle-reduce); (2) wave-uniform all-ones v_mask
// fast path skips bias math (exact: bias==0 when v==1). Slow path = old math.
// qw: [B,H,S,64] bf16 pre-scaled by 0.125*log2e; kw: [B,H,S,64]; vt: [B,H,64,S]
__global__ __launch_bounds__(256, 3) void attn(
    const u16* __restrict__ qw, const u16* __restrict__ kw, const u16* __restrict__ vt,
    const float* __restrict__ v_mask, const float* __restrict__ q_mask,
    float* __restrict__ out) {
    // loop phase:  Ks[2] 16KB | Vs[2] 16KB | bias[2] 512B   (33,280 B)
    // epilogue:    buf 48KB ([4 qs][3 j][16 q][64 d] f32) | lred 1KB
    __shared__ __align__(16) char smem[50176];

    const int tid = threadIdx.x;
    const int lane = tid & 63, w = tid >> 6;
    const int l15 = lane & 15, g = lane >> 4;
    const int w16 = w * 16;
    const int bh = blockIdx.y;
    const int b = bh / HEADS, h = bh % HEADS;
    const int q0 = blockIdx.x * 64;

    const u16* qb = qw + (size_t)bh * SEQ * HD;
    const u16* kb = kw + (size_t)bh * SEQ * HD;
    const u16* vb = vt + (size_t)bh * HD * SEQ;
    const float* vmaskb = v_mask + (size_t)b * SEQ;

    bf16x8 qf[4][2];
#pragma unroll
    for (int qs = 0; qs < 4; ++qs)
#pragma unroll
        for (int kk = 0; kk < 2; ++kk) {
            int row = q0 + qs * 16 + l15;
            qf[qs][kk] = *(const bf16x8*)((const char*)qb + (size_t)row * 128 + kk * 64 + (g << 4));
        }

    // all-ones bf16 A-fragment for the l-sum MFMA
    s16x4 ones4;
#pragma unroll
    for (int r = 0; r < 4; ++r) ones4[r] = (short)0x3F80;

    f32x4 accO[4][4] = {};
    f32x4 lacc[4] = {};            // lacc[qs][r] -> l[q=l15] (all r,g identical)
    float lpart[4];                // filled at epilogue from lacc

    auto stage = [&](int t, int p) {
        const int kv0 = t * 64;
#pragma unroll
        for (int i = 0; i < 2; ++i) {
            int o = (i * 4 + w) * 1024 + lane * 16;
            int row = o >> 7;
            int col = (o & 127) ^ ((row & 7) << 4);
            gld_lds16((const char*)kb + (size_t)(kv0 + row) * 128 + col,
                      smem + p * 8192 + (i * 4 + w) * 1024);
            gld_lds16((const char*)vb + (size_t)row * (SEQ * 2) + (size_t)kv0 * 2 + col,
                      smem + 16384 + p * 8192 + (i * 4 + w) * 1024);
        }
        gld_lds4(vmaskb + kv0 + lane, smem + 32768 + p * 256);
    };

    stage(0, 0);
    __syncthreads();

    for (int t = 0; t < SEQ / 64; ++t) {
        const int cur = t & 1;
        if (t + 1 < SEQ / 64) stage(t + 1, cur ^ 1);
        const char* KsC = smem + cur * 8192;
        const char* VsC = smem + 16384 + cur * 8192;
        const float* biasC = (const float*)(smem + 32768 + cur * 256);

        bf16x8 kf[2];
        {
            int row = w16 + l15;
#pragma unroll
            for (int kk = 0; kk < 2; ++kk)
                kf[kk] = *(const bf16x8*)(KsC + row * 128 +
                                          ((kk * 64 + (g << 4)) ^ ((row & 7) << 4)));
        }
        s16x4 vvf[4];
#pragma unroll
        for (int dt = 0; dt < 4; ++dt) {
            int row = dt * 16 + l15;
            vvf[dt] = *(const s16x4*)(VsC + row * 128 +
                                      ((w16 * 2 + g * 8) ^ ((row & 7) << 4)));
        }
        f32x4 vm = *(const f32x4*)(biasC + w16 + 4 * g);

        f32x4 sc[4] = {};
#pragma unroll
        for (int kk = 0; kk < 2; ++kk)
#pragma unroll
            for (int qs = 0; qs < 4; ++qs)
                sc[qs] = __builtin_amdgcn_mfma_f32_16x16x32_bf16(
                    kf[kk], qf[qs][kk], sc[qs], 0, 0, 0);

        // all-ones fast path for this wave's 16 keys (bias == 0 exactly)
        int mv_ok = (vm[0] == 1.f) & (vm[1] == 1.f) & (vm[2] == 1.f) & (vm[3] == 1.f);
        if (!__all(mv_ok)) {
            f32x4 bbv;
#pragma unroll
            for (int r = 0; r < 4; ++r)
                bbv[r] = fmaf(vm[r], 1.442695e10f, -1.442695e10f);
#pragma unroll
            for (int qs = 0; qs < 4; ++qs)
#pragma unroll
                for (int r = 0; r < 4; ++r)
                    sc[qs][r] += bbv[r];
        }

        s16x4 pb[4];
#pragma unroll
        for (int qs = 0; qs < 4; ++qs)
#pragma unroll
            for (int r = 0; r < 4; ++r)
                pb[qs][r] = (short)f2b(__builtin_amdgcn_exp2f(sc[qs][r]));

        // O partial and l partial (l via ones-MFMA: every C row = column sum)
#pragma unroll
        for (int qs = 0; qs < 4; ++qs) {
#pragma unroll
            for (int dt = 0; dt < 4; ++dt)
                accO[qs][dt] = __builtin_amdgcn_mfma_f32_16x16x16bf16_1k(
                    vvf[dt], pb[qs], accO[qs][dt], 0, 0, 0);
            lacc[qs] = __builtin_amdgcn_mfma_f32_16x16x16bf16_1k(
                ones4, pb[qs], lacc[qs], 0, 0, 0);
        }

        __syncthreads();
    }

#pragma unroll
    for (int qs = 0; qs < 4; ++qs) lpart[qs] = lacc[qs][0];

    float* buf  = (float*)smem;                  // [qs][j][16 q][64 d]
    float* lred = (float*)(smem + 49152);        // [w][qs][16]

    if (g == 0)
#pragma unroll
        for (int qs = 0; qs < 4; ++qs)
            lred[(w * 4 + qs) * 16 + l15] = lpart[qs];

    f32x4 own[4] = {};
#pragma unroll
    for (int qs = 0; qs < 4; ++qs)
        if (qs == w) {
#pragma unroll
            for (int dt = 0; dt < 4; ++dt) own[dt] = accO[qs][dt];
        }

#pragma unroll
    for (int qs = 0; qs < 4; ++qs) {
        if (qs == w) continue;                   // runtime branch, static indices
        int j = (w < qs) ? w : w - 1;
        float* slot = buf + ((qs * 3 + j) * 16 + l15) * 64;
#pragma unroll
        for (int dt = 0; dt < 4; ++dt)
            *(f32x4*)(slot + dt * 16 + 4 * g) = accO[qs][dt];
    }
    __syncthreads();

    {
#pragma unroll
        for (int j = 0; j < 3; ++j) {
            const float* slot = buf + ((w * 3 + j) * 16 + l15) * 64;
#pragma unroll
            for (int dt = 0; dt < 4; ++dt)
                own[dt] += *(const f32x4*)(slot + dt * 16 + 4 * g);
        }
        float ltot = lred[(0 * 4 + w) * 16 + l15] + lred[(1 * 4 + w) * 16 + l15] +
                     lred[(2 * 4 + w) * 16 + l15] + lred[(3 * 4 + w) * 16 + l15];
        int qrow = q0 + w16 + l15;
        float qm = q_mask[(size_t)b * SEQ + qrow];
        float inv = (ltot > 0.f) ? qm / ltot : 0.f;
#pragma unroll
        for (int dt = 0; dt < 4; ++dt) {
            f32x4 o = own[dt] * inv;
            *(f32x4*)(&out[((size_t)b * SEQ + qrow) * 768 + h * HD + dt * 16 + 4 * g]) = o;
        }
    }
}

extern "C" void kernel_launch(void* const* d_in, const int* in_sizes, int n_in,
                              void* d_out, int out_size, void* d_ws, size_t ws_size,
                              hipStream_t stream) {
    const float* q      = (const float*)d_in[0];
    const float* k      = (const float*)d_in[1];
    const float* v      = (const float*)d_in[2];
    const float* vmask  = (const float*)d_in[3];
    const float* qmask  = (const float*)d_in[4];
    const float* Wq     = (const float*)d_in[5];
    const float* Wk     = (const float*)d_in[6];
    const float* Wv     = (const float*)d_in[7];
    float* out = (float*)d_out;

    u16* WTq = (u16*)d_ws;
    u16* WTk = WTq + (size_t)DMODEL * DMODEL;
    u16* WTv = WTk + (size_t)DMODEL * DMODEL;
    u16* qwp = WTv + (size_t)DMODEL * DMODEL;
    u16* kwp = qwp + (size_t)BATCH * HEADS * SEQ * HD;
    u16* vtp = kwp + (size_t)BATCH * HEADS * SEQ * HD;

    cvt_wt<<<dim3(DMODEL / 32, DMODEL / 32, 3), dim3(32, 8), 0, stream>>>(
        Wq, Wk, Wv, WTq, WTk, WTv);
    proj_gemm<<<dim3(BS / 128, DMODEL / 96, 3), 256, 0, stream>>>(
        q, k, v, WTq, WTk, WTv, qwp, kwp, vtp);
    attn<<<dim3(SEQ / 64, BATCH * HEADS), 256, 0, stream>>>(
        qwp, kwp, vtp, vmask, qmask, out);
}